// Round 2
// baseline (191.154 us; speedup 1.0000x reference)
//
#include <hip/hip_runtime.h>
#include <hip/hip_bf16.h>

// out[r] = sum_i cos(x[r][i]) * w[i] + b   (theta unused; RZ leaves <Z> invariant)
// B = 1048576 rows, W = 32 cols. Pure streaming, memory-bound (134 MB read, 4 MB write).
//
// Mapping: 8 lanes per row, each lane owns one float4 (16B). Grid-stride over
// 16 float4s per thread: float4 index f = t + i*TOTAL_THREADS keeps seg = f&7
// constant per lane (TOTAL_THREADS is a multiple of 8), so the w fragment and
// the width-8 shuffle-reduce layout are loop-invariant. 16 independent
// iterations give the scheduler ILP to hide HBM latency; block count drops
// 32768 -> 2048 (8 blocks/CU, one generation).

#define BATCH 1048576
#define WIRES 32
#define BLOCK 256
#define GRID  2048
#define TOTAL_THREADS (GRID * BLOCK)            // 524288, multiple of 8
#define TOTAL_F4 (BATCH * (WIRES / 4))          // 8388608
#define ITERS (TOTAL_F4 / TOTAL_THREADS)        // 16

__global__ __launch_bounds__(BLOCK) void hybrid_regression_kernel(
    const float4* __restrict__ x4,   // BATCH*8 float4s
    const float*  __restrict__ w,    // 32 floats
    const float*  __restrict__ bias, // 1 float
    float*        __restrict__ out)  // BATCH floats
{
    const int t   = blockIdx.x * BLOCK + threadIdx.x;
    const int seg = threadIdx.x & 7;               // quarter-of-row, loop-invariant

    const float4 wv = ((const float4*)w)[seg];
    const float  bb = bias[0];

#pragma unroll 4
    for (int i = 0; i < ITERS; ++i) {
        const int f = t + i * TOTAL_THREADS;       // global float4 index, coalesced
        const float4 v = x4[f];

        float p = __cosf(v.x) * wv.x
                + __cosf(v.y) * wv.y
                + __cosf(v.z) * wv.z
                + __cosf(v.w) * wv.w;

        // reduce across the 8 lanes covering this row
        p += __shfl_down(p, 4, 8);
        p += __shfl_down(p, 2, 8);
        p += __shfl_down(p, 1, 8);

        if (seg == 0) {
            out[f >> 3] = p + bb;
        }
    }
}

extern "C" void kernel_launch(void* const* d_in, const int* in_sizes, int n_in,
                              void* d_out, int out_size, void* d_ws, size_t ws_size,
                              hipStream_t stream) {
    const float* x    = (const float*)d_in[0];
    // d_in[1] = theta, unused (RZ phase does not affect <Z>)
    const float* w    = (const float*)d_in[2];
    const float* bias = (const float*)d_in[3];
    float* out        = (float*)d_out;

    hybrid_regression_kernel<<<GRID, BLOCK, 0, stream>>>(
        (const float4*)x, w, bias, out);
}